// Round 1
// baseline (2763.295 us; speedup 1.0000x reference)
//
#include <hip/hip_runtime.h>

#define NT 64
#define NH 12
#define HD 32
#define DIM 384
#define NWIN 4096
#define TPB 512
#define PTPB 256
#define PROWS 64

typedef __bf16 bf16;
typedef __bf16 bf16x8 __attribute__((ext_vector_type(8)));
typedef __bf16 bf16x4 __attribute__((ext_vector_type(4)));
typedef float floatx4 __attribute__((ext_vector_type(4)));

// bf16 copies of the weight matrices (rewritten every kernel_launch; idempotent).
__device__ bf16 g_wqkv[3 * DIM * DIM];   // [1152][384] row-major, row = output channel
__device__ bf16 g_wproj[DIM * DIM];      // [384][384]  row-major, row = output channel

__global__ void convert_weights(const float* __restrict__ qkv_w,
                                const float* __restrict__ proj_w) {
    int i = blockIdx.x * blockDim.x + threadIdx.x;
    if (i < 3 * DIM * DIM) g_wqkv[i] = (bf16)qkv_w[i];
    if (i < DIM * DIM)     g_wproj[i] = (bf16)proj_w[i];
}

// One block per window. 8 waves. Fused qkv GEMM + bias + scores + rel-pos bias
// + softmax + PV. Writes pre-projection attention output (fp32) to `out`.
__global__ __launch_bounds__(TPB, 2) void attn_kernel(
    const float* __restrict__ x,          // [4096, 64, 384]
    const float* __restrict__ qkv_b,      // [1152]
    const float* __restrict__ bias_table, // [225, 12]
    float* __restrict__ out)              // [4096, 64, 384] attn output (pre-proj)
{
    // 50 KB shared, aliased: sx (staging) is dead after A-fragments are cached
    // in registers, so the per-head buffers reuse its space.
    __shared__ __align__(16) char smem[NT * 392 * 2];
    bf16 (*sx)[392]  = (bf16(*)[392])smem;              // x window, bf16, pad->392 (bank spread)
    bf16 (*sq)[40]   = (bf16(*)[40])(smem);             // q (scaled), rows=token
    bf16 (*sk)[40]   = (bf16(*)[40])(smem + 5120);      // k, rows=token
    bf16 (*svT)[72]  = (bf16(*)[72])(smem + 10240);     // v transposed: [dim][token]
    bf16 (*spb)[72]  = (bf16(*)[72])(smem + 14848);     // softmaxed P, bf16, rows=query
    float (*sp)[66]  = (float(*)[66])(smem + 24064);    // raw scores fp32

    const int t    = threadIdx.x;
    const int win  = blockIdx.x;
    const int wave = t >> 6;
    const int lane = t & 63;
    const int quad = lane >> 4;
    const int l15  = lane & 15;

    // ---- stage x -> bf16 LDS (coalesced float4) ----
    {
        const float4* src = (const float4*)(x + (size_t)win * (NT * DIM));
        #pragma unroll
        for (int it = 0; it < (NT * DIM / 4) / TPB; ++it) {
            int i = t + it * TPB;
            float4 fv = src[i];
            int r = i / (DIM / 4);
            int c = (i % (DIM / 4)) * 4;
            bf16x4 bv;
            bv[0] = (bf16)fv.x; bv[1] = (bf16)fv.y;
            bv[2] = (bf16)fv.z; bv[3] = (bf16)fv.w;
            *(bf16x4*)&sx[r][c] = bv;
        }
    }
    __syncthreads();

    // ---- cache this wave's A-fragments (rows mt*16..mt*16+15, full K=384) ----
    const int mt   = wave & 3;       // m-tile this wave owns for the qkv GEMM
    const int half = wave >> 2;      // selects nt-range {0,1,2} or {3,4,5}
    bf16x8 afrag[DIM / 32];
    #pragma unroll
    for (int ks = 0; ks < DIM / 32; ++ks)
        afrag[ks] = *(const bf16x8*)&sx[mt * 16 + l15][ks * 32 + quad * 8];
    __syncthreads();   // sx dead from here; sq/sk/svT/sp/spb may overwrite it

    const float scale = 0.17677669529663687f;  // 32^-0.5
    float* outw = out + (size_t)win * (NT * DIM);

    #pragma unroll 1
    for (int h = 0; h < NH; ++h) {
        // ---- QKV GEMM: 24 tile jobs (4 m-tiles x 6 n-tiles), 3 per wave ----
        #pragma unroll
        for (int jj = 0; jj < 3; ++jj) {
            int nt = half * 3 + jj;          // 0..5
            int s  = nt >> 1;                // 0=q 1=k 2=v
            int nh = (nt & 1) * 16;          // 0 or 16 within head-dim 32
            int wrow = s * DIM + h * HD + nh + l15;
            const bf16* Wp = g_wqkv + (size_t)wrow * DIM + quad * 8;
            floatx4 acc = {0.f, 0.f, 0.f, 0.f};
            #pragma unroll
            for (int ks = 0; ks < DIM / 32; ++ks) {
                bf16x8 b = *(const bf16x8*)(Wp + ks * 32);
                acc = __builtin_amdgcn_mfma_f32_16x16x32_bf16(afrag[ks], b, acc, 0, 0, 0);
            }
            float bv = qkv_b[wrow];
            #pragma unroll
            for (int r = 0; r < 4; ++r) {
                int m = mt * 16 + quad * 4 + r;
                float v = acc[r] + bv;
                if (s == 0)      sq[m][nh + l15] = (bf16)(v * scale);
                else if (s == 1) sk[m][nh + l15] = (bf16)v;
                else             svT[nh + l15][m] = (bf16)v;
            }
        }
        __syncthreads();

        // ---- scores QK^T: 16 tiles (K=32, single mfma), 2 per wave ----
        #pragma unroll
        for (int jj = 0; jj < 2; ++jj) {
            int job = wave + jj * 8;
            int it = job & 3, jt = job >> 2;
            bf16x8 a = *(const bf16x8*)&sq[it * 16 + l15][quad * 8];
            bf16x8 b = *(const bf16x8*)&sk[jt * 16 + l15][quad * 8];
            floatx4 acc = {0.f, 0.f, 0.f, 0.f};
            acc = __builtin_amdgcn_mfma_f32_16x16x32_bf16(a, b, acc, 0, 0, 0);
            #pragma unroll
            for (int r = 0; r < 4; ++r) {
                int i = it * 16 + quad * 4 + r;
                int j = jt * 16 + l15;
                int yi = i >> 3, xi = i & 7, yj = j >> 3, xj = j & 7;
                int idx = (yi - yj + 7) * 15 + (xi - xj + 7);
                sp[i][j] = acc[r] + bias_table[idx * NH + h];
            }
        }
        __syncthreads();

        // ---- softmax: 8 threads per row, shfl reductions ----
        {
            int r = t >> 3;
            int o = (t & 7) * 8;
            float e[8];
            float mx = -1e30f;
            #pragma unroll
            for (int c = 0; c < 8; ++c) { e[c] = sp[r][o + c]; mx = fmaxf(mx, e[c]); }
            mx = fmaxf(mx, __shfl_xor(mx, 1));
            mx = fmaxf(mx, __shfl_xor(mx, 2));
            mx = fmaxf(mx, __shfl_xor(mx, 4));
            float sum = 0.f;
            #pragma unroll
            for (int c = 0; c < 8; ++c) { e[c] = __expf(e[c] - mx); sum += e[c]; }
            sum += __shfl_xor(sum, 1);
            sum += __shfl_xor(sum, 2);
            sum += __shfl_xor(sum, 4);
            float inv = 1.0f / sum;
            bf16x8 pv;
            #pragma unroll
            for (int c = 0; c < 8; ++c) pv[c] = (bf16)(e[c] * inv);
            *(bf16x8*)&spb[r][o] = pv;
        }
        __syncthreads();

        // ---- PV: 8 tiles (4 m x 2 n), 1 per wave, K=64 ----
        {
            int pmt = wave & 3, pnt = wave >> 2;
            floatx4 acc = {0.f, 0.f, 0.f, 0.f};
            #pragma unroll
            for (int ks = 0; ks < 2; ++ks) {
                bf16x8 a = *(const bf16x8*)&spb[pmt * 16 + l15][ks * 32 + quad * 8];
                bf16x8 b = *(const bf16x8*)&svT[pnt * 16 + l15][ks * 32 + quad * 8];
                acc = __builtin_amdgcn_mfma_f32_16x16x32_bf16(a, b, acc, 0, 0, 0);
            }
            #pragma unroll
            for (int r = 0; r < 4; ++r) {
                int m = pmt * 16 + quad * 4 + r;
                outw[(size_t)m * DIM + h * HD + pnt * 16 + l15] = acc[r];
            }
        }
        __syncthreads();  // protect sq/sk/svT/sp/spb for next head
    }
}

// In-place projection GEMM on `out`: each block owns 64 rows (stage->LDS bf16,
// sync, compute, overwrite the same rows — row-wise op, so in-place is safe).
__global__ __launch_bounds__(PTPB, 2) void proj_kernel(
    const float* __restrict__ proj_b,
    float* __restrict__ out)
{
    __shared__ __align__(16) bf16 sa[PROWS][392];
    const int t    = threadIdx.x;
    const int wave = t >> 6;
    const int lane = t & 63;
    const int quad = lane >> 4;
    const int l15  = lane & 15;
    float* base = out + (size_t)blockIdx.x * (PROWS * DIM);

    {
        const float4* src = (const float4*)base;
        #pragma unroll
        for (int it = 0; it < (PROWS * DIM / 4) / PTPB; ++it) {
            int i = t + it * PTPB;
            float4 fv = src[i];
            int r = i / (DIM / 4);
            int c = (i % (DIM / 4)) * 4;
            bf16x4 bv;
            bv[0] = (bf16)fv.x; bv[1] = (bf16)fv.y;
            bv[2] = (bf16)fv.z; bv[3] = (bf16)fv.w;
            *(bf16x4*)&sa[r][c] = bv;
        }
    }
    __syncthreads();

    // Wave owns m-tile = wave; A-fragments cached in registers (K=384).
    bf16x8 afrag[DIM / 32];
    #pragma unroll
    for (int ks = 0; ks < DIM / 32; ++ks)
        afrag[ks] = *(const bf16x8*)&sa[wave * 16 + l15][ks * 32 + quad * 8];

    #pragma unroll 1
    for (int nt = 0; nt < DIM / 16; ++nt) {
        const bf16* Wp = g_wproj + (size_t)(nt * 16 + l15) * DIM + quad * 8;
        floatx4 acc = {0.f, 0.f, 0.f, 0.f};
        #pragma unroll
        for (int ks = 0; ks < DIM / 32; ++ks) {
            bf16x8 b = *(const bf16x8*)(Wp + ks * 32);
            acc = __builtin_amdgcn_mfma_f32_16x16x32_bf16(afrag[ks], b, acc, 0, 0, 0);
        }
        float pb = proj_b[nt * 16 + l15];
        #pragma unroll
        for (int r = 0; r < 4; ++r)
            base[(size_t)(wave * 16 + quad * 4 + r) * DIM + nt * 16 + l15] = acc[r] + pb;
    }
}

extern "C" void kernel_launch(void* const* d_in, const int* in_sizes, int n_in,
                              void* d_out, int out_size, void* d_ws, size_t ws_size,
                              hipStream_t stream) {
    const float* x          = (const float*)d_in[0];
    const float* qkv_w      = (const float*)d_in[1];
    const float* qkv_b      = (const float*)d_in[2];
    const float* proj_w     = (const float*)d_in[3];
    const float* proj_b     = (const float*)d_in[4];
    const float* bias_table = (const float*)d_in[5];
    float* out = (float*)d_out;

    convert_weights<<<dim3((3 * DIM * DIM + 255) / 256), dim3(256), 0, stream>>>(qkv_w, proj_w);
    attn_kernel<<<dim3(NWIN), dim3(TPB), 0, stream>>>(x, qkv_b, bias_table, out);
    proj_kernel<<<dim3(NWIN), dim3(PTPB), 0, stream>>>(proj_b, out);
}

// Round 2
// 2649.293 us; speedup vs baseline: 1.0430x; 1.0430x over previous
//
#include <hip/hip_runtime.h>

#define NT 64
#define NH 12
#define HD 32
#define DIM 384
#define NWIN 4096
#define TPB 512
#define PTPB 256

typedef __bf16 bf16;
typedef __bf16 bf16x8 __attribute__((ext_vector_type(8)));
typedef __bf16 bf16x4 __attribute__((ext_vector_type(4)));
typedef float floatx4 __attribute__((ext_vector_type(4)));

// bf16 weights + transposed bias table (rewritten every launch; idempotent).
__device__ __align__(16) bf16 g_wqkv[3 * DIM * DIM];   // [1152][384] row = out-channel
__device__ __align__(16) bf16 g_wproj[DIM * DIM];      // [384][384]  row = out-channel
__device__ __align__(16) float g_biasT[NH * 225];      // [12][225]

__global__ void convert_weights(const float* __restrict__ qkv_w,
                                const float* __restrict__ proj_w,
                                const float* __restrict__ bias_table) {
    int i = blockIdx.x * blockDim.x + threadIdx.x;
    if (i < 3 * DIM * DIM) g_wqkv[i] = (bf16)qkv_w[i];
    if (i < DIM * DIM)     g_wproj[i] = (bf16)proj_w[i];
    if (i < NH * 225) {
        int h = i / 225, ix = i % 225;
        g_biasT[i] = bias_table[ix * NH + h];
    }
}

// One block per window, 8 waves, 2 heads per barrier-phase group.
// LDS layout (65,288 B total, sx aliases the front):
//   sx    [64][392] bf16   50,176  (x staging; dead after afrag cache)
//   sq2   [2][64][40] bf16 10,240  @ 0
//   sk2   [2][64][40] bf16 10,240  @ 10,240
//   svT2  [2][32][72] bf16  9,216  @ 20,480
//   sp2   [2][64][66] f32  33,792  @ 29,696  (spb bf16 aliases row-wise)
//   sbias [2][225]   f32    1,800  @ 63,488
__global__ __launch_bounds__(TPB, 4) void attn_kernel(
    const float* __restrict__ x,          // [4096, 64, 384]
    const float* __restrict__ qkv_b,      // [1152]
    float* __restrict__ out)              // [4096, 64, 384] pre-proj attn out
{
    __shared__ __align__(16) char smem[65288];
    bf16 (*sx)[392]      = (bf16(*)[392])smem;
    bf16 (*sq2)[64][40]  = (bf16(*)[64][40])smem;
    bf16 (*sk2)[64][40]  = (bf16(*)[64][40])(smem + 10240);
    bf16 (*svT2)[32][72] = (bf16(*)[32][72])(smem + 20480);
    float (*sp2)[64][66] = (float(*)[64][66])(smem + 29696);
    float (*sbias)[225]  = (float(*)[225])(smem + 63488);

    const int t    = threadIdx.x;
    const int win  = blockIdx.x;
    const int wave = t >> 6;
    const int lane = t & 63;
    const int quad = lane >> 4;
    const int l15  = lane & 15;

    // ---- stage x -> bf16 LDS (coalesced float4) ----
    {
        const float4* src = (const float4*)(x + (size_t)win * (NT * DIM));
        #pragma unroll
        for (int it = 0; it < (NT * DIM / 4) / TPB; ++it) {
            int i = t + it * TPB;
            float4 fv = src[i];
            int r = i / (DIM / 4);
            int c = (i % (DIM / 4)) * 4;
            bf16x4 bv;
            bv[0] = (bf16)fv.x; bv[1] = (bf16)fv.y;
            bv[2] = (bf16)fv.z; bv[3] = (bf16)fv.w;
            *(bf16x4*)&sx[r][c] = bv;
        }
    }
    __syncthreads();

    // ---- cache this wave's A-fragments (one m-tile, full K=384) ----
    const int mt  = wave & 3;
    const int grp = wave >> 2;     // nt-range selector {0,1}
    bf16x8 afrag[DIM / 32];
    #pragma unroll
    for (int ks = 0; ks < DIM / 32; ++ks)
        afrag[ks] = *(const bf16x8*)&sx[mt * 16 + l15][ks * 32 + quad * 8];
    __syncthreads();   // sx dead; attention buffers may overwrite

    const float scale = 0.17677669529663687f;  // 32^-0.5
    float* outw = out + (size_t)win * (NT * DIM);

    #pragma unroll 1
    for (int hp = 0; hp < NH / 2; ++hp) {
        // ---- stage the two heads' bias rows into LDS (covered by next barrier) ----
        if (t < 225)                      sbias[0][t]       = g_biasT[(hp * 2 + 0) * 225 + t];
        else if (t >= 256 && t < 481)     sbias[1][t - 256] = g_biasT[(hp * 2 + 1) * 225 + (t - 256)];

        // ---- QKV GEMM: 48 tile jobs (2 heads x 4 m x 6 n), 6 per wave ----
        #pragma unroll
        for (int jj = 0; jj < 6; ++jj) {
            const int hl  = jj / 3;
            const int j3  = jj % 3;
            const int nt  = grp * 3 + j3;        // 0..5
            const int s   = nt >> 1;             // 0=q 1=k 2=v
            const int nhh = (nt & 1) * 16;
            const int h   = hp * 2 + hl;
            const int wrow = s * DIM + h * HD + nhh + l15;
            const bf16* Wp = g_wqkv + (size_t)wrow * DIM + quad * 8;
            // hoist all 12 B-fragments (pipelined L2 loads), then MFMA chain
            bf16x8 b[12];
            #pragma unroll
            for (int ks = 0; ks < 12; ++ks) b[ks] = *(const bf16x8*)(Wp + ks * 32);
            floatx4 acc = {0.f, 0.f, 0.f, 0.f};
            #pragma unroll
            for (int ks = 0; ks < 12; ++ks)
                acc = __builtin_amdgcn_mfma_f32_16x16x32_bf16(afrag[ks], b[ks], acc, 0, 0, 0);
            float bv = qkv_b[wrow];
            #pragma unroll
            for (int r = 0; r < 4; ++r) {
                int m = mt * 16 + quad * 4 + r;
                float v = acc[r] + bv;
                if (s == 0)      sq2[hl][m][nhh + l15] = (bf16)(v * scale);
                else if (s == 1) sk2[hl][m][nhh + l15] = (bf16)v;
                else             svT2[hl][nhh + l15][m] = (bf16)v;
            }
        }
        __syncthreads();

        // ---- scores QK^T + bias: 32 tiles (2 heads x 16), 4 per wave ----
        #pragma unroll
        for (int jj = 0; jj < 4; ++jj) {
            int job = wave + jj * 8;             // 0..31
            int hl = job >> 4;
            int j4 = job & 15;
            int it = j4 & 3, jt = j4 >> 2;
            bf16x8 a = *(const bf16x8*)&sq2[hl][it * 16 + l15][quad * 8];
            bf16x8 b = *(const bf16x8*)&sk2[hl][jt * 16 + l15][quad * 8];
            floatx4 acc = {0.f, 0.f, 0.f, 0.f};
            acc = __builtin_amdgcn_mfma_f32_16x16x32_bf16(a, b, acc, 0, 0, 0);
            #pragma unroll
            for (int r = 0; r < 4; ++r) {
                int i = it * 16 + quad * 4 + r;
                int j = jt * 16 + l15;
                int yi = i >> 3, xi = i & 7, yj = j >> 3, xj = j & 7;
                int idx = (yi - yj + 7) * 15 + (xi - xj + 7);
                sp2[hl][i][j] = acc[r] + sbias[hl][idx];
            }
        }
        __syncthreads();

        // ---- softmax: 4 threads per row (128 rows), shfl over quad ----
        {
            int r4 = t >> 2;               // 0..127
            int hl = r4 >> 6;
            int r  = r4 & 63;
            int o  = (t & 3) * 16;
            const float2* pr = (const float2*)&sp2[hl][r][0];
            float e[16];
            float mx = -1e30f;
            #pragma unroll
            for (int c = 0; c < 8; ++c) {
                float2 f2 = pr[(o >> 1) + c];
                e[2 * c] = f2.x; e[2 * c + 1] = f2.y;
                mx = fmaxf(mx, fmaxf(f2.x, f2.y));
            }
            mx = fmaxf(mx, __shfl_xor(mx, 1));
            mx = fmaxf(mx, __shfl_xor(mx, 2));
            float sum = 0.f;
            #pragma unroll
            for (int c = 0; c < 16; ++c) { e[c] = __expf(e[c] - mx); sum += e[c]; }
            sum += __shfl_xor(sum, 1);
            sum += __shfl_xor(sum, 2);
            float inv = 1.0f / sum;
            bf16* pw = (bf16*)&sp2[hl][r][0];   // spb aliases sp row (within-wave safe)
            #pragma unroll
            for (int k = 0; k < 4; ++k) {
                bf16x4 pv;
                #pragma unroll
                for (int z = 0; z < 4; ++z) pv[z] = (bf16)(e[4 * k + z] * inv);
                *(bf16x4*)&pw[o + 4 * k] = pv;
            }
        }
        __syncthreads();

        // ---- PV: 16 tiles (2 heads x 4 m x 2 n), 2 per wave, K=64 ----
        #pragma unroll
        for (int jj = 0; jj < 2; ++jj) {
            int job = wave + jj * 8;            // 0..15
            int hl = job >> 3;
            int j3 = job & 7;
            int pmt = j3 & 3, pnt = j3 >> 2;
            const bf16* prow = (const bf16*)&sp2[hl][pmt * 16 + l15][0];
            floatx4 acc = {0.f, 0.f, 0.f, 0.f};
            #pragma unroll
            for (int ks = 0; ks < 2; ++ks) {
                bf16x4 a0 = *(const bf16x4*)&prow[ks * 32 + quad * 8];
                bf16x4 a1 = *(const bf16x4*)&prow[ks * 32 + quad * 8 + 4];
                bf16x8 av;
                #pragma unroll
                for (int z = 0; z < 4; ++z) { av[z] = a0[z]; av[z + 4] = a1[z]; }
                bf16x8 b = *(const bf16x8*)&svT2[hl][pnt * 16 + l15][ks * 32 + quad * 8];
                acc = __builtin_amdgcn_mfma_f32_16x16x32_bf16(av, b, acc, 0, 0, 0);
            }
            int h = hp * 2 + hl;
            #pragma unroll
            for (int r = 0; r < 4; ++r) {
                int m = pmt * 16 + quad * 4 + r;
                outw[(size_t)m * DIM + h * HD + pnt * 16 + l15] = acc[r];
            }
        }
        __syncthreads();
    }
}

// In-place projection on `out`: block owns 64 rows. Hoisted B loads + full
// unroll so L2 loads of iteration n+1 overlap MFMAs of iteration n.
__global__ __launch_bounds__(PTPB, 3) void proj_kernel(
    const float* __restrict__ proj_b,
    float* __restrict__ out)
{
    __shared__ __align__(16) bf16 sa[NT][392];
    const int t    = threadIdx.x;
    const int wave = t >> 6;
    const int lane = t & 63;
    const int quad = lane >> 4;
    const int l15  = lane & 15;
    float* base = out + (size_t)blockIdx.x * (NT * DIM);

    {
        const float4* src = (const float4*)base;
        #pragma unroll
        for (int it = 0; it < (NT * DIM / 4) / PTPB; ++it) {
            int i = t + it * PTPB;
            float4 fv = src[i];
            int r = i / (DIM / 4);
            int c = (i % (DIM / 4)) * 4;
            bf16x4 bv;
            bv[0] = (bf16)fv.x; bv[1] = (bf16)fv.y;
            bv[2] = (bf16)fv.z; bv[3] = (bf16)fv.w;
            *(bf16x4*)&sa[r][c] = bv;
        }
    }
    __syncthreads();

    bf16x8 afrag[DIM / 32];
    #pragma unroll
    for (int ks = 0; ks < DIM / 32; ++ks)
        afrag[ks] = *(const bf16x8*)&sa[wave * 16 + l15][ks * 32 + quad * 8];

    #pragma unroll
    for (int nt = 0; nt < DIM / 16; ++nt) {
        const bf16* Wp = g_wproj + (size_t)(nt * 16 + l15) * DIM + quad * 8;
        bf16x8 b[12];
        #pragma unroll
        for (int ks = 0; ks < 12; ++ks) b[ks] = *(const bf16x8*)(Wp + ks * 32);
        floatx4 acc = {0.f, 0.f, 0.f, 0.f};
        #pragma unroll
        for (int ks = 0; ks < 12; ++ks)
            acc = __builtin_amdgcn_mfma_f32_16x16x32_bf16(afrag[ks], b[ks], acc, 0, 0, 0);
        float pb = proj_b[nt * 16 + l15];
        #pragma unroll
        for (int r = 0; r < 4; ++r)
            base[(size_t)(wave * 16 + quad * 4 + r) * DIM + nt * 16 + l15] = acc[r] + pb;
    }
}

extern "C" void kernel_launch(void* const* d_in, const int* in_sizes, int n_in,
                              void* d_out, int out_size, void* d_ws, size_t ws_size,
                              hipStream_t stream) {
    const float* x          = (const float*)d_in[0];
    const float* qkv_w      = (const float*)d_in[1];
    const float* qkv_b      = (const float*)d_in[2];
    const float* proj_w     = (const float*)d_in[3];
    const float* proj_b     = (const float*)d_in[4];
    const float* bias_table = (const float*)d_in[5];
    float* out = (float*)d_out;

    convert_weights<<<dim3((3 * DIM * DIM + 255) / 256), dim3(256), 0, stream>>>(qkv_w, proj_w, bias_table);
    attn_kernel<<<dim3(NWIN), dim3(TPB), 0, stream>>>(x, qkv_b, out);
    proj_kernel<<<dim3(NWIN), dim3(PTPB), 0, stream>>>(proj_b, out);
}